// Round 1
// baseline (253.286 us; speedup 1.0000x reference)
//
#include <hip/hip_runtime.h>
#include <hip/hip_bf16.h>

// FEELModel: pools + triplet loss (fp32) ; TreeLSTM + sim head (bf16 MFMA GEMMs, fp32 accum)
// B=512, L=64, Lq=128, D=M=512, 3M=1536, H=256, O=30

typedef __attribute__((ext_vector_type(8))) short short8;   // 8 bf16 = 4 VGPRs (MFMA A/B frag)
typedef __attribute__((ext_vector_type(4))) float floatx4;  // MFMA C/D frag

__device__ inline ushort f2bf(float f) {            // fp32 -> bf16 bits, RNE
    unsigned u = __float_as_uint(f);
    u += 0x7fffu + ((u >> 16) & 1u);
    return (ushort)(u >> 16);
}
__device__ inline float sigm(float x) { return 1.0f / (1.0f + expf(-x)); }

// ---------------- pools ----------------

// qv = mean_t emb[q_v[b,t]]  (fp32).  grid=512, block=128 (one float4 per thread)
__global__ __launch_bounds__(128) void pool64_kernel(const int* __restrict__ ids,
                                                     const float* __restrict__ emb,
                                                     float* __restrict__ out) {
    int b = blockIdx.x, d4 = threadIdx.x;
    const int* row = ids + b * 64;
    float4 acc = make_float4(0.f, 0.f, 0.f, 0.f);
    for (int t = 0; t < 64; ++t) {
        const float4 v = *(const float4*)(emb + (size_t)row[t] * 512 + d4 * 4);
        acc.x += v.x; acc.y += v.y; acc.z += v.z; acc.w += v.w;
    }
    const float s = 1.0f / 64.0f;
    *(float4*)(out + (size_t)b * 512 + d4 * 4) =
        make_float4(acc.x * s, acc.y * s, acc.z * s, acc.w * s);
}

// loss[b] = sum_i relu(1 - qv.pool(q_ai) + qv.pool(n_ai))   grid=512, block=256
__global__ __launch_bounds__(256) void loss_kernel(
    const int* __restrict__ qa0, const int* __restrict__ na0,
    const int* __restrict__ qa1, const int* __restrict__ na1,
    const int* __restrict__ qa2, const int* __restrict__ na2,
    const float* __restrict__ qv, const float* __restrict__ emb,
    float* __restrict__ loss) {
    int b = blockIdx.x, tid = threadIdx.x;
    __shared__ float sqv[512];
    sqv[tid]       = qv[(size_t)b * 512 + tid];
    sqv[tid + 256] = qv[(size_t)b * 512 + tid + 256];
    __syncthreads();
    const int* arrs[6] = {qa0, na0, qa1, na1, qa2, na2};
    float dots[6];
#pragma unroll
    for (int a = 0; a < 6; ++a) {
        const int* row = arrs[a] + b * 64;
        float acc = 0.f;
        for (int t = 0; t < 64; ++t) {
            const float* e = emb + (size_t)row[t] * 512;
            acc += sqv[tid] * e[tid] + sqv[tid + 256] * e[tid + 256];
        }
        dots[a] = acc;
    }
    __shared__ float red[6][4];
    int lane = tid & 63, wid = tid >> 6;
#pragma unroll
    for (int a = 0; a < 6; ++a) {
        float v = dots[a];
        for (int off = 32; off; off >>= 1) v += __shfl_down(v, off);
        if (lane == 0) red[a][wid] = v;
    }
    __syncthreads();
    if (tid == 0) {
        float l = 0.f;
#pragma unroll
        for (int i = 0; i < 3; ++i) {
            float dq = (red[2*i][0] + red[2*i][1] + red[2*i][2] + red[2*i][3]) * (1.f / 64.f);
            float dn = (red[2*i+1][0] + red[2*i+1][1] + red[2*i+1][2] + red[2*i+1][3]) * (1.f / 64.f);
            l += fmaxf(0.f, 1.f - dq + dn);
        }
        loss[b] = l;
    }
}

// seq pools -> bf16 TreeLSTM inputs. grid = 3*512*4 = 6144, block=128
// Xleaf rows: (t*512+b)*3 + leaf ; XR row t*512+b cols[0:512) = root x
__global__ __launch_bounds__(128) void seq_pool_kernel(
    const int* __restrict__ query, const int* __restrict__ pos, const int* __restrict__ neg,
    const float* __restrict__ emb, ushort* __restrict__ Xleaf, ushort* __restrict__ XR) {
    int g = blockIdx.x;
    int node = g & 3, b = (g >> 2) & 511, t = g >> 11;
    const int* ids = (t == 0 ? query : (t == 1 ? pos : neg)) + b * 128 + node * 32;
    int d4 = threadIdx.x;
    float4 acc = make_float4(0.f, 0.f, 0.f, 0.f);
    for (int k = 0; k < 32; ++k) {
        const float4 v = *(const float4*)(emb + (size_t)ids[k] * 512 + d4 * 4);
        acc.x += v.x; acc.y += v.y; acc.z += v.z; acc.w += v.w;
    }
    const float s = 1.0f / 32.0f;
    ushort4 o;
    o.x = f2bf(acc.x * s); o.y = f2bf(acc.y * s); o.z = f2bf(acc.z * s); o.w = f2bf(acc.w * s);
    if (node < 3) {
        size_t r = ((size_t)(t * 512 + b)) * 3 + node;
        *(ushort4*)(Xleaf + r * 512 + d4 * 4) = o;
    } else {
        size_t r = (size_t)(t * 512 + b);
        *(ushort4*)(XR + r * 1024 + d4 * 4) = o;
    }
}

// ---------------- weight prep (transpose to [N][K] bf16) ----------------

// Wcat_t[n][k] : k<512 -> Wioux[k][n], else Wiouh[k-512][n].  grid 6144
__global__ __launch_bounds__(256) void prep_wcat_kernel(const float* __restrict__ Wioux,
                                                        const float* __restrict__ Wiouh,
                                                        ushort* __restrict__ Wcat_t) {
    int e = blockIdx.x * 256 + threadIdx.x;  // over 1536*1024
    int n = e >> 10, k = e & 1023;
    float v = (k < 512) ? Wioux[(size_t)k * 1536 + n] : Wiouh[(size_t)(k - 512) * 1536 + n];
    Wcat_t[e] = f2bf(v);
}

// generic K=512 transpose: Wt[n*512+k] = W[k*cols+n]
__global__ __launch_bounds__(256) void prep_wt512_kernel(const float* __restrict__ W,
                                                         ushort* __restrict__ Wt, int cols) {
    int e = blockIdx.x * 256 + threadIdx.x;  // over cols*512
    int n = e >> 9, k = e & 511;
    Wt[e] = f2bf(W[(size_t)k * cols + n]);
}

// wsum[h] = sum_o Wwp[h,o]; wsum[256] = sum_o bwp[o].  1 block x 256
__global__ void wsum_kernel(const float* __restrict__ Wwp, const float* __restrict__ bwp,
                            float* __restrict__ wsum) {
    int h = threadIdx.x;
    float s = 0.f;
    for (int o = 0; o < 30; ++o) s += Wwp[h * 30 + o];
    wsum[h] = s;
    if (h == 0) {
        float t = 0.f;
        for (int o = 0; o < 30; ++o) t += bwp[o];
        wsum[256] = t;
    }
}

// ---------------- bf16 MFMA GEMM: C[M,N] = A[M,K] @ Bt[N,K]^T ----------------
// 128x128 tile, BK=32, 4 waves each 64x64 (4x4 frags of 16x16x32).
// All M,N multiples of 128 and K multiples of 32 (checked by caller shapes).
__global__ __launch_bounds__(256) void gemm_bf16(const ushort* __restrict__ A, int lda,
                                                 const ushort* __restrict__ Bt, int ldb,
                                                 float* __restrict__ C, int ldc, int K) {
    __shared__ alignas(16) ushort sA[128][40];  // +8 pad: kills stride-64B bank conflicts
    __shared__ alignas(16) ushort sB[128][40];
    int tid = threadIdx.x;
    int m0 = blockIdx.x * 128, n0 = blockIdx.y * 128;
    int w = tid >> 6, lane = tid & 63;
    int wm = (w >> 1) * 64, wn = (w & 1) * 64;
    int l15 = lane & 15, g = lane >> 4;

    floatx4 acc[4][4] = {};
    int srow = tid >> 2, scol = (tid & 3) * 8;  // staging: 2 rows per thread

    for (int kb = 0; kb < K; kb += 32) {
        uint4 a0 = *(const uint4*)(A + (size_t)(m0 + srow) * lda + kb + scol);
        uint4 a1 = *(const uint4*)(A + (size_t)(m0 + srow + 64) * lda + kb + scol);
        uint4 b0 = *(const uint4*)(Bt + (size_t)(n0 + srow) * ldb + kb + scol);
        uint4 b1 = *(const uint4*)(Bt + (size_t)(n0 + srow + 64) * ldb + kb + scol);
        __syncthreads();
        *(uint4*)&sA[srow][scol] = a0;
        *(uint4*)&sA[srow + 64][scol] = a1;
        *(uint4*)&sB[srow][scol] = b0;
        *(uint4*)&sB[srow + 64][scol] = b1;
        __syncthreads();
        short8 af[4], bf[4];
#pragma unroll
        for (int f = 0; f < 4; ++f) {
            // same k-slot mapping (8 contiguous per lane-group) for A and B:
            // MFMA result invariant to the k permutation as long as both match.
            af[f] = *(const short8*)&sA[wm + f * 16 + l15][g * 8];
            bf[f] = *(const short8*)&sB[wn + f * 16 + l15][g * 8];
        }
#pragma unroll
        for (int i = 0; i < 4; ++i)
#pragma unroll
            for (int j = 0; j < 4; ++j)
                acc[i][j] = __builtin_amdgcn_mfma_f32_16x16x32_bf16(af[i], bf[j], acc[i][j], 0, 0, 0);
    }
    // C/D layout (HW-verified): col = lane&15, row = 4*(lane>>4)+reg
#pragma unroll
    for (int i = 0; i < 4; ++i)
#pragma unroll
        for (int j = 0; j < 4; ++j) {
            int row = m0 + wm + i * 16 + g * 4;
            int col = n0 + wn + j * 16 + l15;
#pragma unroll
            for (int r = 0; r < 4; ++r)
                C[(size_t)(row + r) * ldc + col] = acc[i][j][r];
        }
}

// ---------------- TreeLSTM epilogues ----------------

// leaves: iou = x@Wioux + bioux + biouh (h_sum = 0, fc term = 0)
// c = sig(i)*tanh(u); h = sig(o)*tanh(c); also h_sum into XR cols [512:1024)
__global__ __launch_bounds__(256) void leaf_act_kernel(
    const float* __restrict__ IOU_l, const float* __restrict__ bioux,
    const float* __restrict__ biouh, float* __restrict__ c_l,
    ushort* __restrict__ h_l, ushort* __restrict__ XR) {
    int tb = blockIdx.x, tid = threadIdx.x;
#pragma unroll
    for (int half = 0; half < 2; ++half) {
        int m = tid + half * 256;
        float bi = bioux[m] + biouh[m];
        float bo = bioux[m + 512] + biouh[m + 512];
        float bu = bioux[m + 1024] + biouh[m + 1024];
        float hs = 0.f;
#pragma unroll
        for (int leaf = 0; leaf < 3; ++leaf) {
            size_t r = (size_t)tb * 3 + leaf;
            const float* row = IOU_l + r * 1536;
            float iv = sigm(row[m] + bi);
            float ov = sigm(row[m + 512] + bo);
            float uv = tanhf(row[m + 1024] + bu);
            float c = iv * uv;
            c_l[r * 512 + m] = c;
            float h = ov * tanhf(c);
            h_l[r * 512 + m] = f2bf(h);
            hs += h;
        }
        XR[(size_t)tb * 1024 + 512 + m] = f2bf(hs);
    }
}

// root: c = sig(i)*tanh(u) + sum_k sig(FH[k]+bfh+FX+bfx)*c_l[k]   (h_root unused)
__global__ __launch_bounds__(256) void root_act_kernel(
    const float* __restrict__ IOU_r, const float* __restrict__ FH,
    const float* __restrict__ FX, const float* __restrict__ c_l,
    const float* __restrict__ bioux, const float* __restrict__ biouh,
    const float* __restrict__ bfx, const float* __restrict__ bfh,
    float* __restrict__ c_root) {
    int r = blockIdx.x, tid = threadIdx.x;
#pragma unroll
    for (int half = 0; half < 2; ++half) {
        int m = tid + half * 256;
        float iv = sigm(IOU_r[(size_t)r * 1536 + m] + bioux[m] + biouh[m]);
        float uv = tanhf(IOU_r[(size_t)r * 1536 + 1024 + m] + bioux[1024 + m] + biouh[1024 + m]);
        float fx = FX[(size_t)r * 512 + m] + bfx[m];
        float c = iv * uv;
#pragma unroll
        for (int k = 0; k < 3; ++k) {
            size_t idx = ((size_t)r * 3 + k) * 512 + m;
            float f = sigm(FH[idx] + bfh[m] + fx);
            c += f * c_l[idx];
        }
        c_root[(size_t)r * 512 + m] = c;
    }
}

// P rows [0:512) = qc*pc ; rows [512:1024) = qc*nc   (bf16). grid 2048
__global__ __launch_bounds__(256) void prod_kernel(const float* __restrict__ c_root,
                                                   ushort* __restrict__ P) {
    int e = blockIdx.x * 256 + threadIdx.x;  // over 1024*512
    int row = e >> 9, n = e & 511;
    int b = row & 511, which = row >> 9;  // 0 -> pc, 1 -> nc
    float q = c_root[(size_t)b * 512 + n];
    float o = c_root[((size_t)(which + 1) * 512 + b) * 512 + n];
    P[e] = f2bf(q * o);
}

// out[b] = loss[b] + relu(1 - a + bb), a = sum_h sig(S[b,h]+bwh[h])*wsum[h] + bsum
__global__ __launch_bounds__(256) void final_kernel(
    const float* __restrict__ S, const float* __restrict__ bwh,
    const float* __restrict__ wsum, const float* __restrict__ loss,
    float* __restrict__ out) {
    int b = blockIdx.x, tid = threadIdx.x;
    float w = wsum[tid];
    float bw = bwh[tid];
    float va = sigm(S[(size_t)b * 256 + tid] + bw) * w;
    float vb = sigm(S[(size_t)(512 + b) * 256 + tid] + bw) * w;
    int lane = tid & 63, wid = tid >> 6;
    for (int off = 32; off; off >>= 1) {
        va += __shfl_down(va, off);
        vb += __shfl_down(vb, off);
    }
    __shared__ float ra[4], rb[4];
    if (lane == 0) { ra[wid] = va; rb[wid] = vb; }
    __syncthreads();
    if (tid == 0) {
        float a  = ra[0] + ra[1] + ra[2] + ra[3] + wsum[256];
        float bb = rb[0] + rb[1] + rb[2] + rb[3] + wsum[256];
        out[b] = loss[b] + fmaxf(0.f, 1.f - a + bb);
    }
}

// ---------------- launch ----------------

extern "C" void kernel_launch(void* const* d_in, const int* in_sizes, int n_in,
                              void* d_out, int out_size, void* d_ws, size_t ws_size,
                              hipStream_t stream) {
    const int* q_v   = (const int*)d_in[0];
    const int* q_a0  = (const int*)d_in[1];
    const int* n_a0  = (const int*)d_in[2];
    const int* q_a1  = (const int*)d_in[3];
    const int* n_a1  = (const int*)d_in[4];
    const int* q_a2  = (const int*)d_in[5];
    const int* n_a2  = (const int*)d_in[6];
    const int* query = (const int*)d_in[7];
    const int* pos   = (const int*)d_in[8];
    const int* neg   = (const int*)d_in[9];
    const float* emb   = (const float*)d_in[10];
    const float* Wioux = (const float*)d_in[11];
    const float* bioux = (const float*)d_in[12];
    const float* Wiouh = (const float*)d_in[13];
    const float* biouh = (const float*)d_in[14];
    const float* Wfx   = (const float*)d_in[15];
    const float* bfx   = (const float*)d_in[16];
    const float* Wfh   = (const float*)d_in[17];
    const float* bfh   = (const float*)d_in[18];
    const float* Wwh   = (const float*)d_in[19];
    const float* bwh   = (const float*)d_in[20];
    const float* Wwp   = (const float*)d_in[21];
    const float* bwp   = (const float*)d_in[22];
    float* out = (float*)d_out;

    char* w = (char*)d_ws;
    auto alloc = [&](size_t bytes) -> void* {
        void* p = (void*)w;
        w += (bytes + 255) & ~(size_t)255;
        return p;
    };
    float*  qv     = (float*) alloc((size_t)512 * 512 * 4);
    float*  loss   = (float*) alloc(512 * 4);
    ushort* Wcat_t = (ushort*)alloc((size_t)1536 * 1024 * 2);
    ushort* Wfh_t  = (ushort*)alloc((size_t)512 * 512 * 2);
    ushort* Wfx_t  = (ushort*)alloc((size_t)512 * 512 * 2);
    ushort* Wwh_t  = (ushort*)alloc((size_t)256 * 512 * 2);
    float*  wsum   = (float*) alloc(257 * 4);
    ushort* Xleaf  = (ushort*)alloc((size_t)4608 * 512 * 2);
    ushort* XR     = (ushort*)alloc((size_t)1536 * 1024 * 2);
    float*  IOU_l  = (float*) alloc((size_t)4608 * 1536 * 4);
    float*  c_l    = (float*) alloc((size_t)4608 * 512 * 4);
    ushort* h_l    = (ushort*)alloc((size_t)4608 * 512 * 2);
    float*  FH     = (float*) alloc((size_t)4608 * 512 * 4);
    float*  FX     = (float*) alloc((size_t)1536 * 512 * 4);
    float*  IOU_r  = (float*) alloc((size_t)1536 * 1536 * 4);
    float*  c_root = (float*) alloc((size_t)1536 * 512 * 4);
    ushort* P      = (ushort*)alloc((size_t)1024 * 512 * 2);
    float*  S      = (float*) alloc((size_t)1024 * 256 * 4);

    // weight prep
    prep_wcat_kernel<<<6144, 256, 0, stream>>>(Wioux, Wiouh, Wcat_t);
    prep_wt512_kernel<<<1024, 256, 0, stream>>>(Wfh, Wfh_t, 512);
    prep_wt512_kernel<<<1024, 256, 0, stream>>>(Wfx, Wfx_t, 512);
    prep_wt512_kernel<<<512, 256, 0, stream>>>(Wwh, Wwh_t, 256);
    wsum_kernel<<<1, 256, 0, stream>>>(Wwp, bwp, wsum);

    // pools + loss (fp32 path)
    pool64_kernel<<<512, 128, 0, stream>>>(q_v, emb, qv);
    loss_kernel<<<512, 256, 0, stream>>>(q_a0, n_a0, q_a1, n_a1, q_a2, n_a2, qv, emb, loss);
    seq_pool_kernel<<<6144, 128, 0, stream>>>(query, pos, neg, emb, Xleaf, XR);

    // TreeLSTM
    // G1: leaves IOU = Xleaf[4608,512] @ Wioux[512,1536]  (Wcat_t rows, first 512 k, ldb=1024)
    gemm_bf16<<<dim3(36, 12), 256, 0, stream>>>(Xleaf, 512, Wcat_t, 1024, IOU_l, 1536, 512);
    leaf_act_kernel<<<1536, 256, 0, stream>>>(IOU_l, bioux, biouh, c_l, h_l, XR);
    // G2: FH = h_l[4608,512] @ Wfh[512,512]
    gemm_bf16<<<dim3(36, 4), 256, 0, stream>>>(h_l, 512, Wfh_t, 512, FH, 512, 512);
    // G3: FX = x_root[1536,512] @ Wfx[512,512]   (XR cols [0:512), lda=1024)
    gemm_bf16<<<dim3(12, 4), 256, 0, stream>>>(XR, 1024, Wfx_t, 512, FX, 512, 512);
    // G4: root IOU = [x_root | h_sum][1536,1024] @ [Wioux;Wiouh][1024,1536]
    gemm_bf16<<<dim3(12, 12), 256, 0, stream>>>(XR, 1024, Wcat_t, 1024, IOU_r, 1536, 1024);
    root_act_kernel<<<1536, 256, 0, stream>>>(IOU_r, FH, FX, c_l, bioux, biouh, bfx, bfh, c_root);

    // sim head
    prod_kernel<<<2048, 256, 0, stream>>>(c_root, P);
    // G5: S = P[1024,512] @ Wwh[512,256]
    gemm_bf16<<<dim3(8, 2), 256, 0, stream>>>(P, 512, Wwh_t, 512, S, 256, 512);
    final_kernel<<<512, 256, 0, stream>>>(S, bwh, wsum, loss, out);
}

// Round 2
// 211.408 us; speedup vs baseline: 1.1981x; 1.1981x over previous
//
#include <hip/hip_runtime.h>
#include <hip/hip_bf16.h>

// FEELModel: bf16 emb table + fused gathers (fp32 accum); TreeLSTM + sim head via bf16 MFMA.
// B=512, L=64, Lq=128, D=M=512, 3M=1536, H=256, O=30

typedef __attribute__((ext_vector_type(8))) short short8;   // 8 bf16
typedef __attribute__((ext_vector_type(4))) float floatx4;  // MFMA C/D frag

__device__ inline ushort f2bf(float f) {            // fp32 -> bf16 bits, RNE
    unsigned u = __float_as_uint(f);
    u += 0x7fffu + ((u >> 16) & 1u);
    return (ushort)(u >> 16);
}
__device__ inline float bf2f(ushort u) { return __uint_as_float((unsigned)u << 16); }
__device__ inline float sigm(float x) { return 1.0f / (1.0f + expf(-x)); }

#define GLD16(gp, sp)                                                        \
    __builtin_amdgcn_global_load_lds(                                        \
        (const __attribute__((address_space(1))) unsigned int*)(const void*)(gp), \
        (__attribute__((address_space(3))) unsigned int*)(void*)(sp), 16, 0, 0)

// ---------------- emb fp32 -> bf16 (one streaming pass) ----------------
// 50000*512 = 25.6M elems, 8 per thread. grid 12500 x 256.
__global__ __launch_bounds__(256) void conv_emb_kernel(const float* __restrict__ emb,
                                                       ushort* __restrict__ emb_bf) {
    size_t i = ((size_t)blockIdx.x * 256 + threadIdx.x) * 8;
    float4 a = *(const float4*)(emb + i);
    float4 b = *(const float4*)(emb + i + 4);
    short8 o;
    o[0] = (short)f2bf(a.x); o[1] = (short)f2bf(a.y); o[2] = (short)f2bf(a.z); o[3] = (short)f2bf(a.w);
    o[4] = (short)f2bf(b.x); o[5] = (short)f2bf(b.y); o[6] = (short)f2bf(b.z); o[7] = (short)f2bf(b.w);
    *(short8*)(emb_bf + i) = o;
}

// ---------------- mega gather: all pools in one kernel ----------------
// Blocks [0,3584): attr pools, s = blk/512 in {q_v,qa0,na0,qa1,na1,qa2,na2}, 64 tokens -> fp32 pools[s][b][512]
// Blocks [3584,9728): tree node pools, 32 tokens -> bf16 Xleaf / XR
// Block = 256 threads: c = tid&63 (16B chunk of the 1KB bf16 row), g = tid>>6 (token group).
__global__ __launch_bounds__(256) void mega_gather_kernel(
    const int* __restrict__ q_v,
    const int* __restrict__ qa0, const int* __restrict__ na0,
    const int* __restrict__ qa1, const int* __restrict__ na1,
    const int* __restrict__ qa2, const int* __restrict__ na2,
    const int* __restrict__ query, const int* __restrict__ pos, const int* __restrict__ neg,
    const ushort* __restrict__ emb_bf,
    float* __restrict__ pools, ushort* __restrict__ Xleaf, ushort* __restrict__ XR) {
    __shared__ float sm[256][9];
    int tid = threadIdx.x;
    int c = tid & 63, g = tid >> 6;
    float acc[8] = {};
    if (blockIdx.x < 3584) {
        int s = blockIdx.x >> 9, b = blockIdx.x & 511;
        const int* aptr[7] = {q_v, qa0, na0, qa1, na1, qa2, na2};
        const int* ids = aptr[s] + b * 64 + g * 16;
#pragma unroll 4
        for (int t = 0; t < 16; ++t) {
            const short8 v = *(const short8*)(emb_bf + (size_t)ids[t] * 512 + c * 8);
#pragma unroll
            for (int k = 0; k < 8; ++k) acc[k] += bf2f((ushort)v[k]);
        }
#pragma unroll
        for (int k = 0; k < 8; ++k) sm[tid][k] = acc[k];
        __syncthreads();
        if (tid < 64) {
#pragma unroll
            for (int gg = 1; gg < 4; ++gg)
#pragma unroll
                for (int k = 0; k < 8; ++k) acc[k] += sm[tid + gg * 64][k];
            const float sc = 1.0f / 64.0f;
            float* dst = pools + ((size_t)s * 512 + b) * 512 + tid * 8;
            *(float4*)dst = make_float4(acc[0] * sc, acc[1] * sc, acc[2] * sc, acc[3] * sc);
            *(float4*)(dst + 4) = make_float4(acc[4] * sc, acc[5] * sc, acc[6] * sc, acc[7] * sc);
        }
    } else {
        int idx = blockIdx.x - 3584;
        int t = idx >> 11, rem = idx & 2047, b = rem >> 2, node = rem & 3;
        const int* sptr[3] = {query, pos, neg};
        const int* ids = sptr[t] + b * 128 + node * 32 + g * 8;
#pragma unroll
        for (int k = 0; k < 8; ++k) {
            const short8 v = *(const short8*)(emb_bf + (size_t)ids[k] * 512 + c * 8);
#pragma unroll
            for (int j = 0; j < 8; ++j) acc[j] += bf2f((ushort)v[j]);
        }
#pragma unroll
        for (int k = 0; k < 8; ++k) sm[tid][k] = acc[k];
        __syncthreads();
        if (tid < 64) {
#pragma unroll
            for (int gg = 1; gg < 4; ++gg)
#pragma unroll
                for (int k = 0; k < 8; ++k) acc[k] += sm[tid + gg * 64][k];
            const float sc = 1.0f / 32.0f;
            short8 o;
#pragma unroll
            for (int k = 0; k < 8; ++k) o[k] = (short)f2bf(acc[k] * sc);
            if (node < 3) {
                size_t r = ((size_t)(t * 512 + b)) * 3 + node;
                *(short8*)(Xleaf + r * 512 + tid * 8) = o;
            } else {
                size_t r = (size_t)(t * 512 + b);
                *(short8*)(XR + r * 1024 + tid * 8) = o;
            }
        }
    }
}

// loss[b] = sum_i relu(1 - qv.pool(q_ai) + qv.pool(n_ai))  from materialized pools. grid 512
__global__ __launch_bounds__(256) void dots_kernel(const float* __restrict__ pools,
                                                   float* __restrict__ loss) {
    int b = blockIdx.x, tid = threadIdx.x;
    const float* pq = pools + (size_t)b * 512;
    float q0 = pq[tid], q1 = pq[tid + 256];
    float d[6];
#pragma unroll
    for (int a = 0; a < 6; ++a) {
        const float* pa = pools + ((size_t)(a + 1) * 512 + b) * 512;
        d[a] = q0 * pa[tid] + q1 * pa[tid + 256];
    }
    __shared__ float red[6][4];
    int lane = tid & 63, wid = tid >> 6;
#pragma unroll
    for (int a = 0; a < 6; ++a) {
        float v = d[a];
        for (int off = 32; off; off >>= 1) v += __shfl_down(v, off);
        if (lane == 0) red[a][wid] = v;
    }
    __syncthreads();
    if (tid == 0) {
        float l = 0.f;
#pragma unroll
        for (int i = 0; i < 3; ++i) {
            float dq = red[2*i][0] + red[2*i][1] + red[2*i][2] + red[2*i][3];
            float dn = red[2*i+1][0] + red[2*i+1][1] + red[2*i+1][2] + red[2*i+1][3];
            l += fmaxf(0.f, 1.f - dq + dn);
        }
        loss[b] = l;
    }
}

// ---------------- weight prep (transpose to [N][K] bf16) ----------------

__global__ __launch_bounds__(256) void prep_wcat_kernel(const float* __restrict__ Wioux,
                                                        const float* __restrict__ Wiouh,
                                                        ushort* __restrict__ Wcat_t) {
    int e = blockIdx.x * 256 + threadIdx.x;  // over 1536*1024
    int n = e >> 10, k = e & 1023;
    float v = (k < 512) ? Wioux[(size_t)k * 1536 + n] : Wiouh[(size_t)(k - 512) * 1536 + n];
    Wcat_t[e] = f2bf(v);
}

__global__ __launch_bounds__(256) void prep_wt512_kernel(const float* __restrict__ W,
                                                         ushort* __restrict__ Wt, int cols) {
    int e = blockIdx.x * 256 + threadIdx.x;  // over cols*512
    int n = e >> 9, k = e & 511;
    Wt[e] = f2bf(W[(size_t)k * cols + n]);
}

__global__ void wsum_kernel(const float* __restrict__ Wwp, const float* __restrict__ bwp,
                            float* __restrict__ wsum) {
    int h = threadIdx.x;
    float s = 0.f;
    for (int o = 0; o < 30; ++o) s += Wwp[h * 30 + o];
    wsum[h] = s;
    if (h == 0) {
        float t = 0.f;
        for (int o = 0; o < 30; ++o) t += bwp[o];
        wsum[256] = t;
    }
}

// ---------------- bf16 MFMA GEMM: C[M,N] = A[M,K] @ Bt[N,K]^T ----------------
// 128x128 tile, BK=32, 4 waves each 64x64 (4x4 frags of 16x16x32).
// m97 structure: global_load_lds width-16 staging into linear LDS, 2 barriers/K-step.
__global__ __launch_bounds__(256) void gemm_bf16(const ushort* __restrict__ A, int lda,
                                                 const ushort* __restrict__ Bt, int ldb,
                                                 float* __restrict__ C, int ldc, int K) {
    __shared__ alignas(16) ushort sA[128 * 32];  // [row][32] bf16, 64B/row, linear (gload_lds)
    __shared__ alignas(16) ushort sB[128 * 32];
    int tid = threadIdx.x;
    int m0 = blockIdx.x * 128, n0 = blockIdx.y * 128;
    int w = tid >> 6, lane = tid & 63;
    int wm = (w >> 1) * 64, wn = (w & 1) * 64;
    int l15 = lane & 15, g = lane >> 4;
    int srow = tid >> 2, scol = (tid & 3) * 8;  // lane deposits at wavebase + lane*16B

    const ushort* Ag0 = A + (size_t)(m0 + srow) * lda + scol;
    const ushort* Ag1 = A + (size_t)(m0 + srow + 64) * lda + scol;
    const ushort* Bg0 = Bt + (size_t)(n0 + srow) * ldb + scol;
    const ushort* Bg1 = Bt + (size_t)(n0 + srow + 64) * ldb + scol;
    ushort* sA0 = sA + w * 512;         // wave-uniform LDS bases (1KB per wave)
    ushort* sA1 = sA + 2048 + w * 512;
    ushort* sB0 = sB + w * 512;
    ushort* sB1 = sB + 2048 + w * 512;

    floatx4 acc[4][4] = {};

    for (int kb = 0; kb < K; kb += 32) {
        __syncthreads();           // prev tile fully consumed
        GLD16(Ag0 + kb, sA0);
        GLD16(Ag1 + kb, sA1);
        GLD16(Bg0 + kb, sB0);
        GLD16(Bg1 + kb, sB1);
        __syncthreads();           // vmcnt(0) drained before barrier -> tile ready
        short8 af[4], bf[4];
#pragma unroll
        for (int f = 0; f < 4; ++f) {
            af[f] = *(const short8*)(sA + (wm + f * 16 + l15) * 32 + g * 8);
            bf[f] = *(const short8*)(sB + (wn + f * 16 + l15) * 32 + g * 8);
        }
#pragma unroll
        for (int i = 0; i < 4; ++i)
#pragma unroll
            for (int j = 0; j < 4; ++j)
                acc[i][j] = __builtin_amdgcn_mfma_f32_16x16x32_bf16(af[i], bf[j], acc[i][j], 0, 0, 0);
    }
    // C/D layout (HW-verified): col = lane&15, row = 4*(lane>>4)+reg
#pragma unroll
    for (int i = 0; i < 4; ++i)
#pragma unroll
        for (int j = 0; j < 4; ++j) {
            int row = m0 + wm + i * 16 + g * 4;
            int col = n0 + wn + j * 16 + l15;
#pragma unroll
            for (int r = 0; r < 4; ++r)
                C[(size_t)(row + r) * ldc + col] = acc[i][j][r];
        }
}

// ---------------- TreeLSTM epilogues ----------------

__global__ __launch_bounds__(256) void leaf_act_kernel(
    const float* __restrict__ IOU_l, const float* __restrict__ bioux,
    const float* __restrict__ biouh, float* __restrict__ c_l,
    ushort* __restrict__ h_l, ushort* __restrict__ XR) {
    int tb = blockIdx.x, tid = threadIdx.x;
#pragma unroll
    for (int half = 0; half < 2; ++half) {
        int m = tid + half * 256;
        float bi = bioux[m] + biouh[m];
        float bo = bioux[m + 512] + biouh[m + 512];
        float bu = bioux[m + 1024] + biouh[m + 1024];
        float hs = 0.f;
#pragma unroll
        for (int leaf = 0; leaf < 3; ++leaf) {
            size_t r = (size_t)tb * 3 + leaf;
            const float* row = IOU_l + r * 1536;
            float iv = sigm(row[m] + bi);
            float ov = sigm(row[m + 512] + bo);
            float uv = tanhf(row[m + 1024] + bu);
            float c = iv * uv;
            c_l[r * 512 + m] = c;
            float h = ov * tanhf(c);
            h_l[r * 512 + m] = f2bf(h);
            hs += h;
        }
        XR[(size_t)tb * 1024 + 512 + m] = f2bf(hs);
    }
}

__global__ __launch_bounds__(256) void root_act_kernel(
    const float* __restrict__ IOU_r, const float* __restrict__ FH,
    const float* __restrict__ FX, const float* __restrict__ c_l,
    const float* __restrict__ bioux, const float* __restrict__ biouh,
    const float* __restrict__ bfx, const float* __restrict__ bfh,
    float* __restrict__ c_root) {
    int r = blockIdx.x, tid = threadIdx.x;
#pragma unroll
    for (int half = 0; half < 2; ++half) {
        int m = tid + half * 256;
        float iv = sigm(IOU_r[(size_t)r * 1536 + m] + bioux[m] + biouh[m]);
        float uv = tanhf(IOU_r[(size_t)r * 1536 + 1024 + m] + bioux[1024 + m] + biouh[1024 + m]);
        float fx = FX[(size_t)r * 512 + m] + bfx[m];
        float c = iv * uv;
#pragma unroll
        for (int k = 0; k < 3; ++k) {
            size_t idx = ((size_t)r * 3 + k) * 512 + m;
            float f = sigm(FH[idx] + bfh[m] + fx);
            c += f * c_l[idx];
        }
        c_root[(size_t)r * 512 + m] = c;
    }
}

__global__ __launch_bounds__(256) void prod_kernel(const float* __restrict__ c_root,
                                                   ushort* __restrict__ P) {
    int e = blockIdx.x * 256 + threadIdx.x;  // over 1024*512
    int row = e >> 9, n = e & 511;
    int b = row & 511, which = row >> 9;  // 0 -> pc, 1 -> nc
    float q = c_root[(size_t)b * 512 + n];
    float o = c_root[((size_t)(which + 1) * 512 + b) * 512 + n];
    P[e] = f2bf(q * o);
}

__global__ __launch_bounds__(256) void final_kernel(
    const float* __restrict__ S, const float* __restrict__ bwh,
    const float* __restrict__ wsum, const float* __restrict__ loss,
    float* __restrict__ out) {
    int b = blockIdx.x, tid = threadIdx.x;
    float w = wsum[tid];
    float bw = bwh[tid];
    float va = sigm(S[(size_t)b * 256 + tid] + bw) * w;
    float vb = sigm(S[(size_t)(512 + b) * 256 + tid] + bw) * w;
    int lane = tid & 63, wid = tid >> 6;
    for (int off = 32; off; off >>= 1) {
        va += __shfl_down(va, off);
        vb += __shfl_down(vb, off);
    }
    __shared__ float ra[4], rb[4];
    if (lane == 0) { ra[wid] = va; rb[wid] = vb; }
    __syncthreads();
    if (tid == 0) {
        float a  = ra[0] + ra[1] + ra[2] + ra[3] + wsum[256];
        float bb = rb[0] + rb[1] + rb[2] + rb[3] + wsum[256];
        out[b] = loss[b] + fmaxf(0.f, 1.f - a + bb);
    }
}

// ---------------- launch ----------------

extern "C" void kernel_launch(void* const* d_in, const int* in_sizes, int n_in,
                              void* d_out, int out_size, void* d_ws, size_t ws_size,
                              hipStream_t stream) {
    const int* q_v   = (const int*)d_in[0];
    const int* q_a0  = (const int*)d_in[1];
    const int* n_a0  = (const int*)d_in[2];
    const int* q_a1  = (const int*)d_in[3];
    const int* n_a1  = (const int*)d_in[4];
    const int* q_a2  = (const int*)d_in[5];
    const int* n_a2  = (const int*)d_in[6];
    const int* query = (const int*)d_in[7];
    const int* pos   = (const int*)d_in[8];
    const int* neg   = (const int*)d_in[9];
    const float* emb   = (const float*)d_in[10];
    const float* Wioux = (const float*)d_in[11];
    const float* bioux = (const float*)d_in[12];
    const float* Wiouh = (const float*)d_in[13];
    const float* biouh = (const float*)d_in[14];
    const float* Wfx   = (const float*)d_in[15];
    const float* bfx   = (const float*)d_in[16];
    const float* Wfh   = (const float*)d_in[17];
    const float* bfh   = (const float*)d_in[18];
    const float* Wwh   = (const float*)d_in[19];
    const float* bwh   = (const float*)d_in[20];
    const float* Wwp   = (const float*)d_in[21];
    const float* bwp   = (const float*)d_in[22];
    float* out = (float*)d_out;

    char* w = (char*)d_ws;
    size_t off = 0;
    auto alloc = [&](size_t bytes) -> void* {
        void* p = (void*)(w + off);
        off = (off + bytes + 255) & ~(size_t)255;
        return p;
    };
    // ---- persistent region ----
    ushort* Wcat_t = (ushort*)alloc((size_t)1536 * 1024 * 2);
    ushort* Wfh_t  = (ushort*)alloc((size_t)512 * 512 * 2);
    ushort* Wfx_t  = (ushort*)alloc((size_t)512 * 512 * 2);
    ushort* Wwh_t  = (ushort*)alloc((size_t)256 * 512 * 2);
    float*  wsum   = (float*) alloc(257 * 4);
    float*  lossv  = (float*) alloc(512 * 4);
    ushort* Xleaf  = (ushort*)alloc((size_t)4608 * 512 * 2);
    ushort* XR     = (ushort*)alloc((size_t)1536 * 1024 * 2);
    // ---- aliased region X: phase1 (emb_bf, pools) then phase2 (GEMM temporaries) ----
    size_t xbase = off;
    ushort* emb_bf = (ushort*)alloc((size_t)50000 * 512 * 2);   // phase 1
    float*  pools  = (float*) alloc((size_t)7 * 512 * 512 * 4);
    off = xbase;                                                 // rewind: phase 2 overlaps
    float*  IOU_l  = (float*) alloc((size_t)4608 * 1536 * 4);
    float*  c_l    = (float*) alloc((size_t)4608 * 512 * 4);
    ushort* h_l    = (ushort*)alloc((size_t)4608 * 512 * 2);
    float*  FH     = (float*) alloc((size_t)4608 * 512 * 4);
    float*  FX     = (float*) alloc((size_t)1536 * 512 * 4);
    float*  IOU_r  = (float*) alloc((size_t)1536 * 1536 * 4);
    float*  c_root = (float*) alloc((size_t)1536 * 512 * 4);
    ushort* P      = (ushort*)alloc((size_t)1024 * 512 * 2);
    float*  S      = (float*) alloc((size_t)1024 * 256 * 4);

    // phase 1: table convert + all gathers + loss dots (before any phase-2 write)
    conv_emb_kernel<<<12500, 256, 0, stream>>>(emb, emb_bf);
    prep_wcat_kernel<<<6144, 256, 0, stream>>>(Wioux, Wiouh, Wcat_t);
    prep_wt512_kernel<<<1024, 256, 0, stream>>>(Wfh, Wfh_t, 512);
    prep_wt512_kernel<<<1024, 256, 0, stream>>>(Wfx, Wfx_t, 512);
    prep_wt512_kernel<<<512, 256, 0, stream>>>(Wwh, Wwh_t, 256);
    wsum_kernel<<<1, 256, 0, stream>>>(Wwp, bwp, wsum);
    mega_gather_kernel<<<9728, 256, 0, stream>>>(q_v, q_a0, n_a0, q_a1, n_a1, q_a2, n_a2,
                                                 query, pos, neg, emb_bf, pools, Xleaf, XR);
    dots_kernel<<<512, 256, 0, stream>>>(pools, lossv);

    // phase 2: TreeLSTM (overwrites the emb_bf/pools region)
    gemm_bf16<<<dim3(36, 12), 256, 0, stream>>>(Xleaf, 512, Wcat_t, 1024, IOU_l, 1536, 512);
    leaf_act_kernel<<<1536, 256, 0, stream>>>(IOU_l, bioux, biouh, c_l, h_l, XR);
    gemm_bf16<<<dim3(36, 4), 256, 0, stream>>>(h_l, 512, Wfh_t, 512, FH, 512, 512);
    gemm_bf16<<<dim3(12, 4), 256, 0, stream>>>(XR, 1024, Wfx_t, 512, FX, 512, 512);
    gemm_bf16<<<dim3(12, 12), 256, 0, stream>>>(XR, 1024, Wcat_t, 1024, IOU_r, 1536, 1024);
    root_act_kernel<<<1536, 256, 0, stream>>>(IOU_r, FH, FX, c_l, bioux, biouh, bfx, bfh, c_root);

    // sim head
    prod_kernel<<<2048, 256, 0, stream>>>(c_root, P);
    gemm_bf16<<<dim3(8, 2), 256, 0, stream>>>(P, 512, Wwh_t, 512, S, 256, 512);
    final_kernel<<<512, 256, 0, stream>>>(S, bwh, wsum, lossv, out);
}

// Round 3
// 134.264 us; speedup vs baseline: 1.8865x; 1.5746x over previous
//
#include <hip/hip_runtime.h>
#include <hip/hip_bf16.h>

// FEELModel: fp8 emb table + fused gathers (fp32 accum); TreeLSTM + sim head via bf16 MFMA.
// B=512, L=64, Lq=128, D=M=512, 3M=1536, H=256, O=30

typedef __attribute__((ext_vector_type(8))) short short8;   // 8 bf16
typedef __attribute__((ext_vector_type(4))) float floatx4;  // MFMA C/D frag
typedef __attribute__((ext_vector_type(2))) float floatx2;

__device__ inline ushort f2bf(float f) {            // fp32 -> bf16 bits, RNE
    unsigned u = __float_as_uint(f);
    u += 0x7fffu + ((u >> 16) & 1u);
    return (ushort)(u >> 16);
}
__device__ inline float bf2f(ushort u) { return __uint_as_float((unsigned)u << 16); }
__device__ inline float sigm(float x) { return 1.0f / (1.0f + expf(-x)); }

#if defined(__has_builtin)
#if __has_builtin(__builtin_amdgcn_cvt_pk_f32_fp8) && __has_builtin(__builtin_amdgcn_cvt_pk_fp8_f32)
#define HW_FP8 1
#endif
#endif

#ifndef HW_FP8
// manual e4m3fn encode (round-to-nearest, saturating)
__device__ inline unsigned enc1(float x) {
    float a = fabsf(x);
    unsigned s = (__float_as_uint(x) >> 31) << 7;
    unsigned b = __float_as_uint(a);
    unsigned uexp = b >> 23;
    if (uexp < 121) {                       // |x| < 2^-6 : denormal, quantum 2^-9
        int m = (int)(a * 512.0f + 0.5f);
        if (m >= 8) return s | 0x08u;       // promoted to 2^-6
        return s | (unsigned)m;
    }
    b += 0x00080000u;                        // round mantissa to 3 bits
    unsigned e = b >> 23;
    if (e > 135u) return s | 0x7Eu;          // saturate to 448
    return s | ((e - 120u) << 3) | ((b >> 20) & 7u);
}
__device__ inline float dec1(unsigned v) {
    unsigned s = (v >> 7) & 1u, e = (v >> 3) & 15u, m = v & 7u;
    float r = e ? __uint_as_float(((e + 120u) << 23) | (m << 20))
                : (float)m * 0.001953125f;
    return s ? -r : r;
}
#endif

__device__ inline unsigned pk4(float a, float b, float c, float d) {
#ifdef HW_FP8
    int v = 0;
    v = __builtin_amdgcn_cvt_pk_fp8_f32(a, b, v, false);
    v = __builtin_amdgcn_cvt_pk_fp8_f32(c, d, v, true);
    return (unsigned)v;
#else
    return enc1(a) | (enc1(b) << 8) | (enc1(c) << 16) | (enc1(d) << 24);
#endif
}
__device__ inline void dec4_add(unsigned v, float* acc) {
#ifdef HW_FP8
    floatx2 p0 = __builtin_amdgcn_cvt_pk_f32_fp8(v, false);
    floatx2 p1 = __builtin_amdgcn_cvt_pk_f32_fp8(v, true);
    acc[0] += p0[0]; acc[1] += p0[1]; acc[2] += p1[0]; acc[3] += p1[1];
#else
    acc[0] += dec1(v & 255u); acc[1] += dec1((v >> 8) & 255u);
    acc[2] += dec1((v >> 16) & 255u); acc[3] += dec1(v >> 24);
#endif
}

#define GLD16(gp, sp)                                                        \
    __builtin_amdgcn_global_load_lds(                                        \
        (const __attribute__((address_space(1))) unsigned int*)(const void*)(gp), \
        (__attribute__((address_space(3))) unsigned int*)(void*)(sp), 16, 0, 0)

#define FP8_SCALE 64.0f

// ---------------- mega prep: emb->fp8, coalesced transposes, wsum ----------------
// blocks [0,12500): conv emb fp32->fp8 (x64 scale), 8 elems/thread
// [12500,14036): Wcat transpose (32x48 tiles)   [14036,14292): Wfh   [14292,14548): Wfx
// [14548,14676): Wwh                            [14676]: wsum
__global__ __launch_bounds__(256) void prep_all_kernel(
    const float* __restrict__ emb, unsigned char* __restrict__ emb8,
    const float* __restrict__ Wioux, const float* __restrict__ Wiouh,
    const float* __restrict__ Wfh, const float* __restrict__ Wfx,
    const float* __restrict__ Wwh, const float* __restrict__ Wwp,
    const float* __restrict__ bwp,
    ushort* __restrict__ Wcat_t, ushort* __restrict__ Wfh_t,
    ushort* __restrict__ Wfx_t, ushort* __restrict__ Wwh_t,
    float* __restrict__ wsum) {
    __shared__ float tt[32][33];
    int blk = blockIdx.x, tid = threadIdx.x;
    if (blk < 12500) {
        size_t i = ((size_t)blk * 256 + tid) * 8;
        float4 a = *(const float4*)(emb + i);
        float4 b = *(const float4*)(emb + i + 4);
        uint2 o;
        o.x = pk4(a.x * FP8_SCALE, a.y * FP8_SCALE, a.z * FP8_SCALE, a.w * FP8_SCALE);
        o.y = pk4(b.x * FP8_SCALE, b.y * FP8_SCALE, b.z * FP8_SCALE, b.w * FP8_SCALE);
        *(uint2*)(emb8 + i) = o;
        return;
    }
    int tx = tid & 31, ty = tid >> 5;
    if (blk < 14036) {  // Wcat: logical [1024][1536] -> Wcat_t[1536][1024]
        int idx = blk - 12500;
        int k0 = (idx & 31) * 32, n0 = (idx >> 5) * 32;
#pragma unroll
        for (int r = 0; r < 4; ++r) {
            int k = k0 + ty + r * 8;
            const float* s = (k < 512) ? Wioux + (size_t)k * 1536
                                       : Wiouh + (size_t)(k - 512) * 1536;
            tt[ty + r * 8][tx] = s[n0 + tx];
        }
        __syncthreads();
#pragma unroll
        for (int r = 0; r < 4; ++r)
            Wcat_t[(size_t)(n0 + ty + r * 8) * 1024 + k0 + tx] = f2bf(tt[tx][ty + r * 8]);
        return;
    }
    if (blk < 14676) {  // K=512 transposes -> [N][512]
        const float* W; ushort* Wt; int idx, ncols;
        if (blk < 14292)      { idx = blk - 14036; W = Wfh; Wt = Wfh_t; ncols = 512; }
        else if (blk < 14548) { idx = blk - 14292; W = Wfx; Wt = Wfx_t; ncols = 512; }
        else                  { idx = blk - 14548; W = Wwh; Wt = Wwh_t; ncols = 256; }
        int nt_count = ncols >> 5;
        int k0 = (idx / nt_count) * 32, n0 = (idx % nt_count) * 32;
#pragma unroll
        for (int r = 0; r < 4; ++r)
            tt[ty + r * 8][tx] = W[(size_t)(k0 + ty + r * 8) * ncols + n0 + tx];
        __syncthreads();
#pragma unroll
        for (int r = 0; r < 4; ++r)
            Wt[(size_t)(n0 + ty + r * 8) * 512 + k0 + tx] = f2bf(tt[tx][ty + r * 8]);
        return;
    }
    // wsum
    {
        float s = 0.f;
        for (int o = 0; o < 30; ++o) s += Wwp[tid * 30 + o];
        wsum[tid] = s;
        if (tid == 0) {
            float t = 0.f;
            for (int o = 0; o < 30; ++o) t += bwp[o];
            wsum[256] = t;
        }
    }
}

// ---------------- mega gather (fp8 table) ----------------
// Blocks [0,3584): attr pools (64 tokens) -> fp32 pools[s][b][512]
// Blocks [3584,9728): tree node pools (32 tokens) -> bf16 Xleaf / XR
// 256 thr: c = tid&63 (8B = 8 dims), g = tid>>6 (token group of 16 / 8).
__global__ __launch_bounds__(256) void mega_gather_kernel(
    const int* __restrict__ q_v,
    const int* __restrict__ qa0, const int* __restrict__ na0,
    const int* __restrict__ qa1, const int* __restrict__ na1,
    const int* __restrict__ qa2, const int* __restrict__ na2,
    const int* __restrict__ query, const int* __restrict__ pos, const int* __restrict__ neg,
    const unsigned char* __restrict__ emb8,
    float* __restrict__ pools, ushort* __restrict__ Xleaf, ushort* __restrict__ XR) {
    __shared__ float sm[256][9];
    int tid = threadIdx.x;
    int c = tid & 63, g = tid >> 6;
    float acc[8] = {};
    if (blockIdx.x < 3584) {
        int s = blockIdx.x >> 9, b = blockIdx.x & 511;
        const int* aptr[7] = {q_v, qa0, na0, qa1, na1, qa2, na2};
        const int* ids = aptr[s] + b * 64 + g * 16;
#pragma unroll 8
        for (int t = 0; t < 16; ++t) {
            const uint2 v = *(const uint2*)(emb8 + (size_t)ids[t] * 512 + c * 8);
            dec4_add(v.x, acc);
            dec4_add(v.y, acc + 4);
        }
#pragma unroll
        for (int k = 0; k < 8; ++k) sm[tid][k] = acc[k];
        __syncthreads();
        if (tid < 64) {
#pragma unroll
            for (int gg = 1; gg < 4; ++gg)
#pragma unroll
                for (int k = 0; k < 8; ++k) acc[k] += sm[tid + gg * 64][k];
            const float sc = 1.0f / (64.0f * FP8_SCALE);
            float* dst = pools + ((size_t)s * 512 + b) * 512 + tid * 8;
            *(float4*)dst = make_float4(acc[0] * sc, acc[1] * sc, acc[2] * sc, acc[3] * sc);
            *(float4*)(dst + 4) = make_float4(acc[4] * sc, acc[5] * sc, acc[6] * sc, acc[7] * sc);
        }
    } else {
        int idx = blockIdx.x - 3584;
        int t = idx >> 11, rem = idx & 2047, b = rem >> 2, node = rem & 3;
        const int* sptr[3] = {query, pos, neg};
        const int* ids = sptr[t] + b * 128 + node * 32 + g * 8;
#pragma unroll
        for (int k = 0; k < 8; ++k) {
            const uint2 v = *(const uint2*)(emb8 + (size_t)ids[k] * 512 + c * 8);
            dec4_add(v.x, acc);
            dec4_add(v.y, acc + 4);
        }
#pragma unroll
        for (int k = 0; k < 8; ++k) sm[tid][k] = acc[k];
        __syncthreads();
        if (tid < 64) {
#pragma unroll
            for (int gg = 1; gg < 4; ++gg)
#pragma unroll
                for (int k = 0; k < 8; ++k) acc[k] += sm[tid + gg * 64][k];
            const float sc = 1.0f / (32.0f * FP8_SCALE);
            short8 o;
#pragma unroll
            for (int k = 0; k < 8; ++k) o[k] = (short)f2bf(acc[k] * sc);
            if (node < 3) {
                size_t r = ((size_t)(t * 512 + b)) * 3 + node;
                *(short8*)(Xleaf + r * 512 + tid * 8) = o;
            } else {
                size_t r = (size_t)(t * 512 + b);
                *(short8*)(XR + r * 1024 + tid * 8) = o;
            }
        }
    }
}

// loss[b] = sum_i relu(1 - qv.pool(q_ai) + qv.pool(n_ai))  grid 512
__global__ __launch_bounds__(256) void dots_kernel(const float* __restrict__ pools,
                                                   float* __restrict__ loss) {
    int b = blockIdx.x, tid = threadIdx.x;
    const float* pq = pools + (size_t)b * 512;
    float q0 = pq[tid], q1 = pq[tid + 256];
    float d[6];
#pragma unroll
    for (int a = 0; a < 6; ++a) {
        const float* pa = pools + ((size_t)(a + 1) * 512 + b) * 512;
        d[a] = q0 * pa[tid] + q1 * pa[tid + 256];
    }
    __shared__ float red[6][4];
    int lane = tid & 63, wid = tid >> 6;
#pragma unroll
    for (int a = 0; a < 6; ++a) {
        float v = d[a];
        for (int off = 32; off; off >>= 1) v += __shfl_down(v, off);
        if (lane == 0) red[a][wid] = v;
    }
    __syncthreads();
    if (tid == 0) {
        float l = 0.f;
#pragma unroll
        for (int i = 0; i < 3; ++i) {
            float dq = red[2*i][0] + red[2*i][1] + red[2*i][2] + red[2*i][3];
            float dn = red[2*i+1][0] + red[2*i+1][1] + red[2*i+1][2] + red[2*i+1][3];
            l += fmaxf(0.f, 1.f - dq + dn);
        }
        loss[b] = l;
    }
}

// ---------------- bf16 MFMA GEMM body: C[M,N] = A[M,K] @ Bt[N,K]^T ----------------
// 128x128 tile, BK=32, 4 waves each 64x64 (4x4 frags of 16x16x32). m97 structure.
__device__ __forceinline__ void gemm_body(const ushort* __restrict__ A, int lda,
                                          const ushort* __restrict__ Bt, int ldb,
                                          float* __restrict__ C, int ldc, int K,
                                          int bx, int by, ushort* sA, ushort* sB) {
    int tid = threadIdx.x;
    int m0 = bx * 128, n0 = by * 128;
    int w = tid >> 6, lane = tid & 63;
    int wm = (w >> 1) * 64, wn = (w & 1) * 64;
    int l15 = lane & 15, g = lane >> 4;
    int srow = tid >> 2, scol = (tid & 3) * 8;  // lane deposits at wavebase + lane*16B

    const ushort* Ag0 = A + (size_t)(m0 + srow) * lda + scol;
    const ushort* Ag1 = A + (size_t)(m0 + srow + 64) * lda + scol;
    const ushort* Bg0 = Bt + (size_t)(n0 + srow) * ldb + scol;
    const ushort* Bg1 = Bt + (size_t)(n0 + srow + 64) * ldb + scol;
    ushort* sA0 = sA + w * 512;         // wave-uniform LDS bases (1KB per wave)
    ushort* sA1 = sA + 2048 + w * 512;
    ushort* sB0 = sB + w * 512;
    ushort* sB1 = sB + 2048 + w * 512;

    floatx4 acc[4][4] = {};

    for (int kb = 0; kb < K; kb += 32) {
        __syncthreads();
        GLD16(Ag0 + kb, sA0);
        GLD16(Ag1 + kb, sA1);
        GLD16(Bg0 + kb, sB0);
        GLD16(Bg1 + kb, sB1);
        __syncthreads();
        short8 af[4], bf[4];
#pragma unroll
        for (int f = 0; f < 4; ++f) {
            af[f] = *(const short8*)(sA + (wm + f * 16 + l15) * 32 + g * 8);
            bf[f] = *(const short8*)(sB + (wn + f * 16 + l15) * 32 + g * 8);
        }
#pragma unroll
        for (int i = 0; i < 4; ++i)
#pragma unroll
            for (int j = 0; j < 4; ++j)
                acc[i][j] = __builtin_amdgcn_mfma_f32_16x16x32_bf16(af[i], bf[j], acc[i][j], 0, 0, 0);
    }
    // C/D layout (HW-verified): col = lane&15, row = 4*(lane>>4)+reg
#pragma unroll
    for (int i = 0; i < 4; ++i)
#pragma unroll
        for (int j = 0; j < 4; ++j) {
            int row = m0 + wm + i * 16 + g * 4;
            int col = n0 + wn + j * 16 + l15;
#pragma unroll
            for (int r = 0; r < 4; ++r)
                C[(size_t)(row + r) * ldc + col] = acc[i][j][r];
        }
}

__global__ __launch_bounds__(256) void gemm_bf16(const ushort* __restrict__ A, int lda,
                                                 const ushort* __restrict__ Bt, int ldb,
                                                 float* __restrict__ C, int ldc, int K) {
    __shared__ alignas(16) ushort sA[128 * 32];
    __shared__ alignas(16) ushort sB[128 * 32];
    gemm_body(A, lda, Bt, ldb, C, ldc, K, blockIdx.x, blockIdx.y, sA, sB);
}

// G2 (FH, 36x4) + G3 (FX, 12x4) + G4 (IOU_r, 12x12) in one 336-block launch
__global__ __launch_bounds__(256) void gemm3_bf16(
    const ushort* __restrict__ h_l, const ushort* __restrict__ XR,
    const ushort* __restrict__ Wfh_t, const ushort* __restrict__ Wfx_t,
    const ushort* __restrict__ Wcat_t,
    float* __restrict__ FH, float* __restrict__ FX, float* __restrict__ IOU_r) {
    __shared__ alignas(16) ushort sA[128 * 32];
    __shared__ alignas(16) ushort sB[128 * 32];
    int r = blockIdx.x;
    if (r < 144)      gemm_body(h_l, 512, Wfh_t, 512, FH, 512, 512, r % 36, r / 36, sA, sB);
    else if (r < 192) { int q = r - 144; gemm_body(XR, 1024, Wfx_t, 512, FX, 512, 512, q % 12, q / 12, sA, sB); }
    else              { int q = r - 192; gemm_body(XR, 1024, Wcat_t, 1024, IOU_r, 1536, 1024, q % 12, q / 12, sA, sB); }
}

// ---------------- TreeLSTM epilogues ----------------

__global__ __launch_bounds__(256) void leaf_act_kernel(
    const float* __restrict__ IOU_l, const float* __restrict__ bioux,
    const float* __restrict__ biouh, float* __restrict__ c_l,
    ushort* __restrict__ h_l, ushort* __restrict__ XR) {
    int tb = blockIdx.x, tid = threadIdx.x;
#pragma unroll
    for (int half = 0; half < 2; ++half) {
        int m = tid + half * 256;
        float bi = bioux[m] + biouh[m];
        float bo = bioux[m + 512] + biouh[m + 512];
        float bu = bioux[m + 1024] + biouh[m + 1024];
        float hs = 0.f;
#pragma unroll
        for (int leaf = 0; leaf < 3; ++leaf) {
            size_t r = (size_t)tb * 3 + leaf;
            const float* row = IOU_l + r * 1536;
            float iv = sigm(row[m] + bi);
            float ov = sigm(row[m + 512] + bo);
            float uv = tanhf(row[m + 1024] + bu);
            float c = iv * uv;
            c_l[r * 512 + m] = c;
            float h = ov * tanhf(c);
            h_l[r * 512 + m] = f2bf(h);
            hs += h;
        }
        XR[(size_t)tb * 1024 + 512 + m] = f2bf(hs);
    }
}

__global__ __launch_bounds__(256) void root_act_kernel(
    const float* __restrict__ IOU_r, const float* __restrict__ FH,
    const float* __restrict__ FX, const float* __restrict__ c_l,
    const float* __restrict__ bioux, const float* __restrict__ biouh,
    const float* __restrict__ bfx, const float* __restrict__ bfh,
    float* __restrict__ c_root) {
    int r = blockIdx.x, tid = threadIdx.x;
#pragma unroll
    for (int half = 0; half < 2; ++half) {
        int m = tid + half * 256;
        float iv = sigm(IOU_r[(size_t)r * 1536 + m] + bioux[m] + biouh[m]);
        float uv = tanhf(IOU_r[(size_t)r * 1536 + 1024 + m] + bioux[1024 + m] + biouh[1024 + m]);
        float fx = FX[(size_t)r * 512 + m] + bfx[m];
        float c = iv * uv;
#pragma unroll
        for (int k = 0; k < 3; ++k) {
            size_t idx = ((size_t)r * 3 + k) * 512 + m;
            float f = sigm(FH[idx] + bfh[m] + fx);
            c += f * c_l[idx];
        }
        c_root[(size_t)r * 512 + m] = c;
    }
}

__global__ __launch_bounds__(256) void prod_kernel(const float* __restrict__ c_root,
                                                   ushort* __restrict__ P) {
    int e = blockIdx.x * 256 + threadIdx.x;  // over 1024*512
    int row = e >> 9, n = e & 511;
    int b = row & 511, which = row >> 9;  // 0 -> pc, 1 -> nc
    float q = c_root[(size_t)b * 512 + n];
    float o = c_root[((size_t)(which + 1) * 512 + b) * 512 + n];
    P[e] = f2bf(q * o);
}

__global__ __launch_bounds__(256) void final_kernel(
    const float* __restrict__ S, const float* __restrict__ bwh,
    const float* __restrict__ wsum, const float* __restrict__ loss,
    float* __restrict__ out) {
    int b = blockIdx.x, tid = threadIdx.x;
    float w = wsum[tid];
    float bw = bwh[tid];
    float va = sigm(S[(size_t)b * 256 + tid] + bw) * w;
    float vb = sigm(S[(size_t)(512 + b) * 256 + tid] + bw) * w;
    int lane = tid & 63, wid = tid >> 6;
    for (int off = 32; off; off >>= 1) {
        va += __shfl_down(va, off);
        vb += __shfl_down(vb, off);
    }
    __shared__ float ra[4], rb[4];
    if (lane == 0) { ra[wid] = va; rb[wid] = vb; }
    __syncthreads();
    if (tid == 0) {
        float a  = ra[0] + ra[1] + ra[2] + ra[3] + wsum[256];
        float bb = rb[0] + rb[1] + rb[2] + rb[3] + wsum[256];
        out[b] = loss[b] + fmaxf(0.f, 1.f - a + bb);
    }
}

// ---------------- launch ----------------

extern "C" void kernel_launch(void* const* d_in, const int* in_sizes, int n_in,
                              void* d_out, int out_size, void* d_ws, size_t ws_size,
                              hipStream_t stream) {
    const int* q_v   = (const int*)d_in[0];
    const int* q_a0  = (const int*)d_in[1];
    const int* n_a0  = (const int*)d_in[2];
    const int* q_a1  = (const int*)d_in[3];
    const int* n_a1  = (const int*)d_in[4];
    const int* q_a2  = (const int*)d_in[5];
    const int* n_a2  = (const int*)d_in[6];
    const int* query = (const int*)d_in[7];
    const int* pos   = (const int*)d_in[8];
    const int* neg   = (const int*)d_in[9];
    const float* emb   = (const float*)d_in[10];
    const float* Wioux = (const float*)d_in[11];
    const float* bioux = (const float*)d_in[12];
    const float* Wiouh = (const float*)d_in[13];
    const float* biouh = (const float*)d_in[14];
    const float* Wfx   = (const float*)d_in[15];
    const float* bfx   = (const float*)d_in[16];
    const float* Wfh   = (const float*)d_in[17];
    const float* bfh   = (const float*)d_in[18];
    const float* Wwh   = (const float*)d_in[19];
    const float* bwh   = (const float*)d_in[20];
    const float* Wwp   = (const float*)d_in[21];
    const float* bwp   = (const float*)d_in[22];
    float* out = (float*)d_out;

    char* w = (char*)d_ws;
    size_t off = 0;
    auto alloc = [&](size_t bytes) -> void* {
        void* p = (void*)(w + off);
        off = (off + bytes + 255) & ~(size_t)255;
        return p;
    };
    // ---- persistent region ----
    ushort* Wcat_t = (ushort*)alloc((size_t)1536 * 1024 * 2);
    ushort* Wfh_t  = (ushort*)alloc((size_t)512 * 512 * 2);
    ushort* Wfx_t  = (ushort*)alloc((size_t)512 * 512 * 2);
    ushort* Wwh_t  = (ushort*)alloc((size_t)256 * 512 * 2);
    float*  wsum   = (float*) alloc(257 * 4);
    float*  lossv  = (float*) alloc(512 * 4);
    ushort* Xleaf  = (ushort*)alloc((size_t)4608 * 512 * 2);
    ushort* XR     = (ushort*)alloc((size_t)1536 * 1024 * 2);
    // ---- aliased region X: phase1 (emb8, pools) then phase2 (GEMM temporaries) ----
    size_t xbase = off;
    unsigned char* emb8 = (unsigned char*)alloc((size_t)50000 * 512);   // phase 1
    float* pools        = (float*)        alloc((size_t)7 * 512 * 512 * 4);
    off = xbase;                                                         // rewind
    float*  IOU_l  = (float*) alloc((size_t)4608 * 1536 * 4);
    float*  c_l    = (float*) alloc((size_t)4608 * 512 * 4);
    ushort* h_l    = (ushort*)alloc((size_t)4608 * 512 * 2);
    float*  FH     = (float*) alloc((size_t)4608 * 512 * 4);
    float*  FX     = (float*) alloc((size_t)1536 * 512 * 4);
    float*  IOU_r  = (float*) alloc((size_t)1536 * 1536 * 4);
    float*  c_root = (float*) alloc((size_t)1536 * 512 * 4);
    ushort* P      = (ushort*)alloc((size_t)1024 * 512 * 2);
    float*  S      = (float*) alloc((size_t)1024 * 256 * 4);

    // phase 1
    prep_all_kernel<<<14677, 256, 0, stream>>>(emb, emb8, Wioux, Wiouh, Wfh, Wfx, Wwh,
                                               Wwp, bwp, Wcat_t, Wfh_t, Wfx_t, Wwh_t, wsum);
    mega_gather_kernel<<<9728, 256, 0, stream>>>(q_v, q_a0, n_a0, q_a1, n_a1, q_a2, n_a2,
                                                 query, pos, neg, emb8, pools, Xleaf, XR);
    dots_kernel<<<512, 256, 0, stream>>>(pools, lossv);

    // phase 2: TreeLSTM (overwrites the emb8/pools region)
    gemm_bf16<<<dim3(36, 12), 256, 0, stream>>>(Xleaf, 512, Wcat_t, 1024, IOU_l, 1536, 512);
    leaf_act_kernel<<<1536, 256, 0, stream>>>(IOU_l, bioux, biouh, c_l, h_l, XR);
    gemm3_bf16<<<336, 256, 0, stream>>>(h_l, XR, Wfh_t, Wfx_t, Wcat_t, FH, FX, IOU_r);
    root_act_kernel<<<1536, 256, 0, stream>>>(IOU_r, FH, FX, c_l, bioux, biouh, bfx, bfh, c_root);

    // sim head
    prod_kernel<<<2048, 256, 0, stream>>>(c_root, P);
    gemm_bf16<<<dim3(8, 2), 256, 0, stream>>>(P, 512, Wwh_t, 512, S, 256, 512);
    final_kernel<<<512, 256, 0, stream>>>(S, bwh, wsum, lossv, out);
}

// Round 4
// 124.490 us; speedup vs baseline: 2.0346x; 1.0785x over previous
//
#include <hip/hip_runtime.h>
#include <hip/hip_bf16.h>

// FEELModel: fp8 emb table + fused gathers (fp32 accum); TreeLSTM + sim head via bf16 MFMA.
// bf16 intermediates, double-buffered 2-phase GEMM, 8 kernels total.
// B=512, L=64, Lq=128, D=M=512, 3M=1536, H=256, O=30

typedef __attribute__((ext_vector_type(8))) short short8;   // 8 bf16
typedef __attribute__((ext_vector_type(4))) float floatx4;  // MFMA C/D frag
typedef __attribute__((ext_vector_type(2))) float floatx2;

__device__ inline ushort f2bf(float f) {            // fp32 -> bf16 bits, RNE
    unsigned u = __float_as_uint(f);
    u += 0x7fffu + ((u >> 16) & 1u);
    return (ushort)(u >> 16);
}
__device__ inline float bf2f(ushort u) { return __uint_as_float((unsigned)u << 16); }
__device__ inline float sigm(float x) { return 1.0f / (1.0f + expf(-x)); }

#if defined(__has_builtin)
#if __has_builtin(__builtin_amdgcn_cvt_pk_f32_fp8) && __has_builtin(__builtin_amdgcn_cvt_pk_fp8_f32)
#define HW_FP8 1
#endif
#endif

#ifndef HW_FP8
// manual e4m3fn encode (round-to-nearest, saturating)
__device__ inline unsigned enc1(float x) {
    float a = fabsf(x);
    unsigned s = (__float_as_uint(x) >> 31) << 7;
    unsigned b = __float_as_uint(a);
    unsigned uexp = b >> 23;
    if (uexp < 121) {                       // |x| < 2^-6 : denormal, quantum 2^-9
        int m = (int)(a * 512.0f + 0.5f);
        if (m >= 8) return s | 0x08u;
        return s | (unsigned)m;
    }
    b += 0x00080000u;
    unsigned e = b >> 23;
    if (e > 135u) return s | 0x7Eu;
    return s | ((e - 120u) << 3) | ((b >> 20) & 7u);
}
__device__ inline float dec1(unsigned v) {
    unsigned s = (v >> 7) & 1u, e = (v >> 3) & 15u, m = v & 7u;
    float r = e ? __uint_as_float(((e + 120u) << 23) | (m << 20))
                : (float)m * 0.001953125f;
    return s ? -r : r;
}
#endif

__device__ inline unsigned pk4(float a, float b, float c, float d) {
#ifdef HW_FP8
    int v = 0;
    v = __builtin_amdgcn_cvt_pk_fp8_f32(a, b, v, false);
    v = __builtin_amdgcn_cvt_pk_fp8_f32(c, d, v, true);
    return (unsigned)v;
#else
    return enc1(a) | (enc1(b) << 8) | (enc1(c) << 16) | (enc1(d) << 24);
#endif
}
__device__ inline void dec4_add(unsigned v, float* acc) {
#ifdef HW_FP8
    floatx2 p0 = __builtin_amdgcn_cvt_pk_f32_fp8(v, false);
    floatx2 p1 = __builtin_amdgcn_cvt_pk_f32_fp8(v, true);
    acc[0] += p0[0]; acc[1] += p0[1]; acc[2] += p1[0]; acc[3] += p1[1];
#else
    acc[0] += dec1(v & 255u); acc[1] += dec1((v >> 8) & 255u);
    acc[2] += dec1((v >> 16) & 255u); acc[3] += dec1(v >> 24);
#endif
}

#define GLD16(gp, sp)                                                        \
    __builtin_amdgcn_global_load_lds(                                        \
        (const __attribute__((address_space(1))) unsigned int*)(const void*)(gp), \
        (__attribute__((address_space(3))) unsigned int*)(void*)(sp), 16, 0, 0)

#define FP8_SCALE 64.0f

// ---------------- mega prep: emb->fp8, coalesced transposes, wsum ----------------
__global__ __launch_bounds__(256) void prep_all_kernel(
    const float* __restrict__ emb, unsigned char* __restrict__ emb8,
    const float* __restrict__ Wioux, const float* __restrict__ Wiouh,
    const float* __restrict__ Wfh, const float* __restrict__ Wfx,
    const float* __restrict__ Wwh, const float* __restrict__ Wwp,
    const float* __restrict__ bwp,
    ushort* __restrict__ Wcat_t, ushort* __restrict__ Wfh_t,
    ushort* __restrict__ Wfx_t, ushort* __restrict__ Wwh_t,
    float* __restrict__ wsum) {
    __shared__ float tt[32][33];
    int blk = blockIdx.x, tid = threadIdx.x;
    if (blk < 12500) {
        size_t i = ((size_t)blk * 256 + tid) * 8;
        float4 a = *(const float4*)(emb + i);
        float4 b = *(const float4*)(emb + i + 4);
        uint2 o;
        o.x = pk4(a.x * FP8_SCALE, a.y * FP8_SCALE, a.z * FP8_SCALE, a.w * FP8_SCALE);
        o.y = pk4(b.x * FP8_SCALE, b.y * FP8_SCALE, b.z * FP8_SCALE, b.w * FP8_SCALE);
        *(uint2*)(emb8 + i) = o;
        return;
    }
    int tx = tid & 31, ty = tid >> 5;
    if (blk < 14036) {  // Wcat: logical [1024][1536] -> Wcat_t[1536][1024]
        int idx = blk - 12500;
        int k0 = (idx & 31) * 32, n0 = (idx >> 5) * 32;
#pragma unroll
        for (int r = 0; r < 4; ++r) {
            int k = k0 + ty + r * 8;
            const float* s = (k < 512) ? Wioux + (size_t)k * 1536
                                       : Wiouh + (size_t)(k - 512) * 1536;
            tt[ty + r * 8][tx] = s[n0 + tx];
        }
        __syncthreads();
#pragma unroll
        for (int r = 0; r < 4; ++r)
            Wcat_t[(size_t)(n0 + ty + r * 8) * 1024 + k0 + tx] = f2bf(tt[tx][ty + r * 8]);
        return;
    }
    if (blk < 14676) {  // K=512 transposes -> [N][512]
        const float* W; ushort* Wt; int idx, ncols;
        if (blk < 14292)      { idx = blk - 14036; W = Wfh; Wt = Wfh_t; ncols = 512; }
        else if (blk < 14548) { idx = blk - 14292; W = Wfx; Wt = Wfx_t; ncols = 512; }
        else                  { idx = blk - 14548; W = Wwh; Wt = Wwh_t; ncols = 256; }
        int nt_count = ncols >> 5;
        int k0 = (idx / nt_count) * 32, n0 = (idx % nt_count) * 32;
#pragma unroll
        for (int r = 0; r < 4; ++r)
            tt[ty + r * 8][tx] = W[(size_t)(k0 + ty + r * 8) * ncols + n0 + tx];
        __syncthreads();
#pragma unroll
        for (int r = 0; r < 4; ++r)
            Wt[(size_t)(n0 + ty + r * 8) * 512 + k0 + tx] = f2bf(tt[tx][ty + r * 8]);
        return;
    }
    {
        float s = 0.f;
        for (int o = 0; o < 30; ++o) s += Wwp[tid * 30 + o];
        wsum[tid] = s;
        if (tid == 0) {
            float t = 0.f;
            for (int o = 0; o < 30; ++o) t += bwp[o];
            wsum[256] = t;
        }
    }
}

// ---------------- mega gather (fp8 table, batch-loads-then-decode) ----------------
__global__ __launch_bounds__(256) void mega_gather_kernel(
    const int* __restrict__ q_v,
    const int* __restrict__ qa0, const int* __restrict__ na0,
    const int* __restrict__ qa1, const int* __restrict__ na1,
    const int* __restrict__ qa2, const int* __restrict__ na2,
    const int* __restrict__ query, const int* __restrict__ pos, const int* __restrict__ neg,
    const unsigned char* __restrict__ emb8,
    float* __restrict__ pools, ushort* __restrict__ Xleaf, ushort* __restrict__ XR) {
    __shared__ float sm[256][9];
    int tid = threadIdx.x;
    int c = tid & 63, g = tid >> 6;
    float acc[8] = {};
    if (blockIdx.x < 3584) {
        int s = blockIdx.x >> 9, b = blockIdx.x & 511;
        const int* aptr[7] = {q_v, qa0, na0, qa1, na1, qa2, na2};
        const int* ids = aptr[s] + b * 64 + g * 16;
        uint2 v[16];
#pragma unroll
        for (int t = 0; t < 16; ++t)
            v[t] = *(const uint2*)(emb8 + (size_t)ids[t] * 512 + c * 8);
#pragma unroll
        for (int t = 0; t < 16; ++t) { dec4_add(v[t].x, acc); dec4_add(v[t].y, acc + 4); }
#pragma unroll
        for (int k = 0; k < 8; ++k) sm[tid][k] = acc[k];
        __syncthreads();
        if (tid < 64) {
#pragma unroll
            for (int gg = 1; gg < 4; ++gg)
#pragma unroll
                for (int k = 0; k < 8; ++k) acc[k] += sm[tid + gg * 64][k];
            const float sc = 1.0f / (64.0f * FP8_SCALE);
            float* dst = pools + ((size_t)s * 512 + b) * 512 + tid * 8;
            *(float4*)dst = make_float4(acc[0] * sc, acc[1] * sc, acc[2] * sc, acc[3] * sc);
            *(float4*)(dst + 4) = make_float4(acc[4] * sc, acc[5] * sc, acc[6] * sc, acc[7] * sc);
        }
    } else {
        int idx = blockIdx.x - 3584;
        int t = idx >> 11, rem = idx & 2047, b = rem >> 2, node = rem & 3;
        const int* sptr[3] = {query, pos, neg};
        const int* ids = sptr[t] + b * 128 + node * 32 + g * 8;
        uint2 v[8];
#pragma unroll
        for (int k = 0; k < 8; ++k)
            v[k] = *(const uint2*)(emb8 + (size_t)ids[k] * 512 + c * 8);
#pragma unroll
        for (int k = 0; k < 8; ++k) { dec4_add(v[k].x, acc); dec4_add(v[k].y, acc + 4); }
#pragma unroll
        for (int k = 0; k < 8; ++k) sm[tid][k] = acc[k];
        __syncthreads();
        if (tid < 64) {
#pragma unroll
            for (int gg = 1; gg < 4; ++gg)
#pragma unroll
                for (int k = 0; k < 8; ++k) acc[k] += sm[tid + gg * 64][k];
            const float sc = 1.0f / (32.0f * FP8_SCALE);
            short8 o;
#pragma unroll
            for (int k = 0; k < 8; ++k) o[k] = (short)f2bf(acc[k] * sc);
            if (node < 3) {
                size_t r = ((size_t)(t * 512 + b)) * 3 + node;
                *(short8*)(Xleaf + r * 512 + tid * 8) = o;
            } else {
                size_t r = (size_t)(t * 512 + b);
                *(short8*)(XR + r * 1024 + tid * 8) = o;
            }
        }
    }
}

// ---------------- bf16 MFMA GEMM body (double-buffered, 1 barrier / K-step) ----------------
// 128x128 tile, BK=32, 4 waves each 64x64. sA/sB each 2 buffers x 4096 ushorts (32 KB total).
__device__ inline void cstore(float* C, size_t idx, float v)  { C[idx] = v; }
__device__ inline void cstore(ushort* C, size_t idx, float v) { C[idx] = f2bf(v); }

template <typename OutT>
__device__ __forceinline__ void gemm_body(const ushort* __restrict__ A, int lda,
                                          const ushort* __restrict__ Bt, int ldb,
                                          OutT* __restrict__ C, int ldc, int K,
                                          int bx, int by, ushort* sA, ushort* sB) {
    int tid = threadIdx.x;
    int m0 = bx * 128, n0 = by * 128;
    int w = tid >> 6, lane = tid & 63;
    int wm = (w >> 1) * 64, wn = (w & 1) * 64;
    int l15 = lane & 15, g = lane >> 4;
    int srow = tid >> 2, scol = (tid & 3) * 8;

    const ushort* Ag0 = A + (size_t)(m0 + srow) * lda + scol;
    const ushort* Ag1 = A + (size_t)(m0 + srow + 64) * lda + scol;
    const ushort* Bg0 = Bt + (size_t)(n0 + srow) * ldb + scol;
    const ushort* Bg1 = Bt + (size_t)(n0 + srow + 64) * ldb + scol;

    floatx4 acc[4][4] = {};

    auto stage = [&](int buf, int kb) {
        ushort* dA = sA + buf * 4096;
        ushort* dB = sB + buf * 4096;
        GLD16(Ag0 + kb, dA + w * 512);
        GLD16(Ag1 + kb, dA + 2048 + w * 512);
        GLD16(Bg0 + kb, dB + w * 512);
        GLD16(Bg1 + kb, dB + 2048 + w * 512);
    };

    stage(0, 0);
    __syncthreads();               // drains vmcnt before first read
    int cur = 0;
    for (int kb = 0; kb < K; kb += 32) {
        if (kb + 32 < K) stage(cur ^ 1, kb + 32);   // prefetch next tile (other buffer)
        const ushort* bA = sA + cur * 4096;
        const ushort* bB = sB + cur * 4096;
        short8 af[4], bf[4];
#pragma unroll
        for (int f = 0; f < 4; ++f) {
            af[f] = *(const short8*)(bA + (wm + f * 16 + l15) * 32 + g * 8);
            bf[f] = *(const short8*)(bB + (wn + f * 16 + l15) * 32 + g * 8);
        }
#pragma unroll
        for (int i = 0; i < 4; ++i)
#pragma unroll
            for (int j = 0; j < 4; ++j)
                acc[i][j] = __builtin_amdgcn_mfma_f32_16x16x32_bf16(af[i], bf[j], acc[i][j], 0, 0, 0);
        __syncthreads();           // next buffer staged + this buffer free for overwrite
        cur ^= 1;
    }
    // C/D layout (HW-verified): col = lane&15, row = 4*(lane>>4)+reg
#pragma unroll
    for (int i = 0; i < 4; ++i)
#pragma unroll
        for (int j = 0; j < 4; ++j) {
            int row = m0 + wm + i * 16 + g * 4;
            int col = n0 + wn + j * 16 + l15;
#pragma unroll
            for (int r = 0; r < 4; ++r)
                cstore(C, (size_t)(row + r) * ldc + col, acc[i][j][r]);
        }
}

// G1 (leaf IOU, 432 blocks) + dots (512 blocks) in one launch
__global__ __launch_bounds__(256) void g1_dots_kernel(
    const ushort* __restrict__ Xleaf, const ushort* __restrict__ Wcat_t,
    ushort* __restrict__ IOU_l,
    const float* __restrict__ pools, float* __restrict__ lossv) {
    __shared__ alignas(16) ushort sA[8192];
    __shared__ alignas(16) ushort sB[8192];
    __shared__ float red[6][4];
    int blk = blockIdx.x, tid = threadIdx.x;
    if (blk < 432) {
        gemm_body(Xleaf, 512, Wcat_t, 1024, IOU_l, 1536, 512, blk % 36, blk / 36, sA, sB);
        return;
    }
    int b = blk - 432;
    const float* pq = pools + (size_t)b * 512;
    float q0 = pq[tid], q1 = pq[tid + 256];
    float d[6];
#pragma unroll
    for (int a = 0; a < 6; ++a) {
        const float* pa = pools + ((size_t)(a + 1) * 512 + b) * 512;
        d[a] = q0 * pa[tid] + q1 * pa[tid + 256];
    }
    int lane = tid & 63, wid = tid >> 6;
#pragma unroll
    for (int a = 0; a < 6; ++a) {
        float v = d[a];
        for (int off = 32; off; off >>= 1) v += __shfl_down(v, off);
        if (lane == 0) red[a][wid] = v;
    }
    __syncthreads();
    if (tid == 0) {
        float l = 0.f;
#pragma unroll
        for (int i = 0; i < 3; ++i) {
            float dq = red[2*i][0] + red[2*i][1] + red[2*i][2] + red[2*i][3];
            float dn = red[2*i+1][0] + red[2*i+1][1] + red[2*i+1][2] + red[2*i+1][3];
            l += fmaxf(0.f, 1.f - dq + dn);
        }
        lossv[b] = l;
    }
}

// G4 (IOU_r, K=1024, blocks 0-143 — longest first) + G2 (FH, 144-287) + G3 (FX, 288-335)
__global__ __launch_bounds__(256) void gemm3_kernel(
    const ushort* __restrict__ h_l, const ushort* __restrict__ XR,
    const ushort* __restrict__ Wfh_t, const ushort* __restrict__ Wfx_t,
    const ushort* __restrict__ Wcat_t,
    ushort* __restrict__ FH, ushort* __restrict__ FX, ushort* __restrict__ IOU_r) {
    __shared__ alignas(16) ushort sA[8192];
    __shared__ alignas(16) ushort sB[8192];
    int r = blockIdx.x;
    if (r < 144)      gemm_body(XR, 1024, Wcat_t, 1024, IOU_r, 1536, 1024, r % 12, r / 12, sA, sB);
    else if (r < 288) { int q = r - 144; gemm_body(h_l, 512, Wfh_t, 512, FH, 512, 512, q % 36, q / 36, sA, sB); }
    else              { int q = r - 288; gemm_body(XR, 1024, Wfx_t, 512, FX, 512, 512, q % 12, q / 12, sA, sB); }
}

// sim GEMM: S[1024,256] = P @ Wwh, P[r][k] = qc[b][k] * (pc|nc)[b][k] computed on the fly.
// A staged via reg+ds_write; B via global_load_lds. 16 blocks.
__global__ __launch_bounds__(256) void gemm_sim_kernel(
    const float* __restrict__ c_root, const ushort* __restrict__ Wwh_t,
    float* __restrict__ S) {
    __shared__ alignas(16) ushort sA[8192];
    __shared__ alignas(16) ushort sB[8192];
    int tid = threadIdx.x;
    int bx = blockIdx.x & 7, by = blockIdx.x >> 3;
    int m0 = bx * 128, n0 = by * 128;
    int w = tid >> 6, lane = tid & 63;
    int wm = (w >> 1) * 64, wn = (w & 1) * 64;
    int l15 = lane & 15, g = lane >> 4;
    int srow = tid >> 2, scol = (tid & 3) * 8;

    const ushort* Bg0 = Wwh_t + (size_t)(n0 + srow) * 512 + scol;
    const ushort* Bg1 = Wwh_t + (size_t)(n0 + srow + 64) * 512 + scol;

    floatx4 acc[4][4] = {};

    auto stage = [&](int buf, int kb) {
        ushort* dA = sA + buf * 4096;
        ushort* dB = sB + buf * 4096;
        GLD16(Bg0 + kb, dB + w * 512);
        GLD16(Bg1 + kb, dB + 2048 + w * 512);
#pragma unroll
        for (int half = 0; half < 2; ++half) {
            int gr = m0 + srow + half * 64;
            int b = gr & 511, which = gr >> 9;
            const float* qrow = c_root + (size_t)b * 512 + kb + scol;
            const float* orow = c_root + ((size_t)(which + 1) * 512 + b) * 512 + kb + scol;
            float4 q0 = *(const float4*)qrow, q1 = *(const float4*)(qrow + 4);
            float4 o0 = *(const float4*)orow, o1 = *(const float4*)(orow + 4);
            short8 pv;
            pv[0] = (short)f2bf(q0.x * o0.x); pv[1] = (short)f2bf(q0.y * o0.y);
            pv[2] = (short)f2bf(q0.z * o0.z); pv[3] = (short)f2bf(q0.w * o0.w);
            pv[4] = (short)f2bf(q1.x * o1.x); pv[5] = (short)f2bf(q1.y * o1.y);
            pv[6] = (short)f2bf(q1.z * o1.z); pv[7] = (short)f2bf(q1.w * o1.w);
            *(short8*)(dA + (srow + half * 64) * 32 + scol) = pv;
        }
    };

    stage(0, 0);
    __syncthreads();
    int cur = 0;
    for (int kb = 0; kb < 512; kb += 32) {
        if (kb + 32 < 512) stage(cur ^ 1, kb + 32);
        const ushort* bA = sA + cur * 4096;
        const ushort* bB = sB + cur * 4096;
        short8 af[4], bf[4];
#pragma unroll
        for (int f = 0; f < 4; ++f) {
            af[f] = *(const short8*)(bA + (wm + f * 16 + l15) * 32 + g * 8);
            bf[f] = *(const short8*)(bB + (wn + f * 16 + l15) * 32 + g * 8);
        }
#pragma unroll
        for (int i = 0; i < 4; ++i)
#pragma unroll
            for (int j = 0; j < 4; ++j)
                acc[i][j] = __builtin_amdgcn_mfma_f32_16x16x32_bf16(af[i], bf[j], acc[i][j], 0, 0, 0);
        __syncthreads();
        cur ^= 1;
    }
#pragma unroll
    for (int i = 0; i < 4; ++i)
#pragma unroll
        for (int j = 0; j < 4; ++j) {
            int row = m0 + wm + i * 16 + g * 4;
            int col = n0 + wn + j * 16 + l15;
#pragma unroll
            for (int r = 0; r < 4; ++r)
                S[(size_t)(row + r) * 256 + col] = acc[i][j][r];
        }
}

// ---------------- TreeLSTM epilogues (bf16 in/out) ----------------

__global__ __launch_bounds__(256) void leaf_act_kernel(
    const ushort* __restrict__ IOU_l, const float* __restrict__ bioux,
    const float* __restrict__ biouh, ushort* __restrict__ c_l,
    ushort* __restrict__ h_l, ushort* __restrict__ XR) {
    int tb = blockIdx.x, tid = threadIdx.x;
#pragma unroll
    for (int half = 0; half < 2; ++half) {
        int m = tid + half * 256;
        float bi = bioux[m] + biouh[m];
        float bo = bioux[m + 512] + biouh[m + 512];
        float bu = bioux[m + 1024] + biouh[m + 1024];
        float hs = 0.f;
#pragma unroll
        for (int leaf = 0; leaf < 3; ++leaf) {
            size_t r = (size_t)tb * 3 + leaf;
            const ushort* row = IOU_l + r * 1536;
            float iv = sigm(bf2f(row[m]) + bi);
            float ov = sigm(bf2f(row[m + 512]) + bo);
            float uv = tanhf(bf2f(row[m + 1024]) + bu);
            float c = iv * uv;
            c_l[r * 512 + m] = f2bf(c);
            float h = ov * tanhf(c);
            h_l[r * 512 + m] = f2bf(h);
            hs += h;
        }
        XR[(size_t)tb * 1024 + 512 + m] = f2bf(hs);
    }
}

__global__ __launch_bounds__(256) void root_act_kernel(
    const ushort* __restrict__ IOU_r, const ushort* __restrict__ FH,
    const ushort* __restrict__ FX, const ushort* __restrict__ c_l,
    const float* __restrict__ bioux, const float* __restrict__ biouh,
    const float* __restrict__ bfx, const float* __restrict__ bfh,
    float* __restrict__ c_root) {
    int r = blockIdx.x, tid = threadIdx.x;
#pragma unroll
    for (int half = 0; half < 2; ++half) {
        int m = tid + half * 256;
        float iv = sigm(bf2f(IOU_r[(size_t)r * 1536 + m]) + bioux[m] + biouh[m]);
        float uv = tanhf(bf2f(IOU_r[(size_t)r * 1536 + 1024 + m]) + bioux[1024 + m] + biouh[1024 + m]);
        float fx = bf2f(FX[(size_t)r * 512 + m]) + bfx[m];
        float c = iv * uv;
#pragma unroll
        for (int k = 0; k < 3; ++k) {
            size_t idx = ((size_t)r * 3 + k) * 512 + m;
            float f = sigm(bf2f(FH[idx]) + bfh[m] + fx);
            c += f * bf2f(c_l[idx]);
        }
        c_root[(size_t)r * 512 + m] = c;
    }
}

__global__ __launch_bounds__(256) void final_kernel(
    const float* __restrict__ S, const float* __restrict__ bwh,
    const float* __restrict__ wsum, const float* __restrict__ loss,
    float* __restrict__ out) {
    int b = blockIdx.x, tid = threadIdx.x;
    float w = wsum[tid];
    float bw = bwh[tid];
    float va = sigm(S[(size_t)b * 256 + tid] + bw) * w;
    float vb = sigm(S[(size_t)(512 + b) * 256 + tid] + bw) * w;
    int lane = tid & 63, wid = tid >> 6;
    for (int off = 32; off; off >>= 1) {
        va += __shfl_down(va, off);
        vb += __shfl_down(vb, off);
    }
    __shared__ float ra[4], rb[4];
    if (lane == 0) { ra[wid] = va; rb[wid] = vb; }
    __syncthreads();
    if (tid == 0) {
        float a  = ra[0] + ra[1] + ra[2] + ra[3] + wsum[256];
        float bb = rb[0] + rb[1] + rb[2] + rb[3] + wsum[256];
        out[b] = loss[b] + fmaxf(0.f, 1.f - a + bb);
    }
}

// ---------------- launch ----------------

extern "C" void kernel_launch(void* const* d_in, const int* in_sizes, int n_in,
                              void* d_out, int out_size, void* d_ws, size_t ws_size,
                              hipStream_t stream) {
    const int* q_v   = (const int*)d_in[0];
    const int* q_a0  = (const int*)d_in[1];
    const int* n_a0  = (const int*)d_in[2];
    const int* q_a1  = (const int*)d_in[3];
    const int* n_a1  = (const int*)d_in[4];
    const int* q_a2  = (const int*)d_in[5];
    const int* n_a2  = (const int*)d_in[6];
    const int* query = (const int*)d_in[7];
    const int* pos   = (const int*)d_in[8];
    const int* neg   = (const int*)d_in[9];
    const float* emb   = (const float*)d_in[10];
    const float* Wioux = (const float*)d_in[11];
    const float* bioux = (const float*)d_in[12];
    const float* Wiouh = (const float*)d_in[13];
    const float* biouh = (const float*)d_in[14];
    const float* Wfx   = (const float*)d_in[15];
    const float* bfx   = (const float*)d_in[16];
    const float* Wfh   = (const float*)d_in[17];
    const float* bfh   = (const float*)d_in[18];
    const float* Wwh   = (const float*)d_in[19];
    const float* bwh   = (const float*)d_in[20];
    const float* Wwp   = (const float*)d_in[21];
    const float* bwp   = (const float*)d_in[22];
    float* out = (float*)d_out;

    char* w = (char*)d_ws;
    size_t off = 0;
    auto alloc = [&](size_t bytes) -> void* {
        void* p = (void*)(w + off);
        off = (off + bytes + 255) & ~(size_t)255;
        return p;
    };
    // ---- persistent region ----
    ushort* Wcat_t = (ushort*)alloc((size_t)1536 * 1024 * 2);
    ushort* Wfh_t  = (ushort*)alloc((size_t)512 * 512 * 2);
    ushort* Wfx_t  = (ushort*)alloc((size_t)512 * 512 * 2);
    ushort* Wwh_t  = (ushort*)alloc((size_t)256 * 512 * 2);
    float*  wsum   = (float*) alloc(257 * 4);
    float*  lossv  = (float*) alloc(512 * 4);
    ushort* Xleaf  = (ushort*)alloc((size_t)4608 * 512 * 2);
    ushort* XR     = (ushort*)alloc((size_t)1536 * 1024 * 2);
    // ---- aliased region X: phase1 (emb8, pools) then phase2 (GEMM temporaries) ----
    size_t xbase = off;
    unsigned char* emb8 = (unsigned char*)alloc((size_t)50000 * 512);
    float* pools        = (float*)        alloc((size_t)7 * 512 * 512 * 4);
    off = xbase;   // rewind: phase 2 overlaps (ordering makes it safe:
                   // emb8 dead after mega_gather; pools dead after g1_dots)
    ushort* IOU_l  = (ushort*)alloc((size_t)4608 * 1536 * 2);   // [xbase, +14.2MB)
    ushort* c_l    = (ushort*)alloc((size_t)4608 * 512 * 2);
    ushort* h_l    = (ushort*)alloc((size_t)4608 * 512 * 2);
    ushort* FH     = (ushort*)alloc((size_t)4608 * 512 * 2);    // overlaps pools tail (dead)
    ushort* FX     = (ushort*)alloc((size_t)1536 * 512 * 2);
    ushort* IOU_r  = (ushort*)alloc((size_t)1536 * 1536 * 2);
    float*  c_root = (float*) alloc((size_t)1536 * 512 * 4);
    float*  S      = (float*) alloc((size_t)1024 * 256 * 4);

    prep_all_kernel<<<14677, 256, 0, stream>>>(emb, emb8, Wioux, Wiouh, Wfh, Wfx, Wwh,
                                               Wwp, bwp, Wcat_t, Wfh_t, Wfx_t, Wwh_t, wsum);
    mega_gather_kernel<<<9728, 256, 0, stream>>>(q_v, q_a0, n_a0, q_a1, n_a1, q_a2, n_a2,
                                                 query, pos, neg, emb8, pools, Xleaf, XR);
    g1_dots_kernel<<<944, 256, 0, stream>>>(Xleaf, Wcat_t, IOU_l, pools, lossv);
    leaf_act_kernel<<<1536, 256, 0, stream>>>(IOU_l, bioux, biouh, c_l, h_l, XR);
    gemm3_kernel<<<336, 256, 0, stream>>>(h_l, XR, Wfh_t, Wfx_t, Wcat_t, FH, FX, IOU_r);
    root_act_kernel<<<1536, 256, 0, stream>>>(IOU_r, FH, FX, c_l, bioux, biouh, bfx, bfh, c_root);
    gemm_sim_kernel<<<16, 256, 0, stream>>>(c_root, Wwh_t, S);
    final_kernel<<<512, 256, 0, stream>>>(S, bwh, wsum, lossv, out);
}